// Round 11
// baseline (44.908 us; speedup 1.0000x reference)
//
#include <hip/hip_runtime.h>
#include <math.h>

#define B_    16384
#define C_    256
#define N_    128
#define M_    20
#define S_    3
#define EMIT_ 26
#define WSTR  26          // W row stride in LDS (floats) == global layout
#define CSTR  68          // c quarter stride in LDS (floats) -> conflict-free
#define GRID_ 1280        // 5 blocks/CU x 256 CUs, all co-resident

// Wave-uniform broadcast into an SGPR.
__device__ __forceinline__ float bcast(float v, int l) {
    return __int_as_float(__builtin_amdgcn_readlane(__float_as_int(v), l));
}

// Async global->LDS DMA, 16B/lane (vmcnt-counted, zero VGPR payload).
__device__ __forceinline__ void dma16(const float* g, float* l) {
    __builtin_amdgcn_global_load_lds(
        (const __attribute__((address_space(1))) void*)g,
        (__attribute__((address_space(3))) void*)l, 16, 0, 0);
}

// PERSISTENT blocks: W staged into LDS ONCE (one barrier total), then each
// wave grid-strides over batch rows with r8's proven per-row body:
//   per-iter vmcnt queue: [2 prev stores][c float4][10x Mt float4][2x w_prev]
//   vmcnt(12) retires stores+c; Mt+wp STAY IN FLIGHT across the LDS-only FC.
// No per-iteration barrier (c strip is same-wave RAW; W is read-only).
__global__ __launch_bounds__(256, 5) void ntm_persist_kernel(
    const float* __restrict__ ctrl,    // (B, C)
    const float* __restrict__ w_prev,  // (B, N)
    const float* __restrict__ Mt,      // (B, N, M)
    const float* __restrict__ W,       // (C, EMIT)
    const float* __restrict__ bvec,    // (EMIT)
    float* __restrict__ out)           // (B, N)
{
    const int lane = threadIdx.x & 63;
    const int wid  = threadIdx.x >> 6;

    __shared__ float W_lds[C_ * WSTR];    // 26624 B, staged once
    __shared__ float c_lds[4][4 * CSTR];  // 4352 B, per-wave strips

    const int jp = lane & 15;
    const int jq = (jp > 12) ? 12 : jp;   // j-pair 0..12 (lanes 13..15 dup)
    const int q  = lane >> 4;             // C quarter

    // loop-invariant bias pair
    const float2 bb = *(const float2*)(bvec + 2 * jq);

    // ---- stage W once: 26 x 1KB chunks over 4 waves ----
    for (int k = wid; k < 26; k += 4)
        dma16(W + k * 256 + lane * 4, W_lds + k * 256);
    asm volatile("s_waitcnt vmcnt(0)" ::: "memory");
    __builtin_amdgcn_s_barrier();
    __builtin_amdgcn_sched_barrier(0);

    const float* Wbase  = &W_lds[(q * 64) * WSTR + 2 * jq];
    float*       cstrip = &c_lds[wid][0];

    for (int grp = blockIdx.x; grp < B_ / 4; grp += GRID_) {
        const int b = grp * 4 + wid;

        // ---- issue loads: c4 (oldest), then Mt x10, then w_prev x2 ----
        const float4 c4 = *(const float4*)(ctrl + (size_t)b * C_ + lane * 4);
        __builtin_amdgcn_sched_barrier(0);
        const float* M0 = Mt + ((size_t)b * N_ + lane) * M_;
        const float* M1 = M0 + (size_t)64 * M_;
        float4 ma[5], mb[5];
        #pragma unroll
        for (int i = 0; i < 5; ++i) ma[i] = *(const float4*)(M0 + 4 * i);
        #pragma unroll
        for (int i = 0; i < 5; ++i) mb[i] = *(const float4*)(M1 + 4 * i);
        const float wp0 = w_prev[(size_t)b * N_ + lane];
        const float wp1 = w_prev[(size_t)b * N_ + lane + 64];
        __builtin_amdgcn_sched_barrier(0);

        // ---- retire (prev stores +) c4 only; Mt(10)+wp(2) stay in flight ----
        asm volatile("s_waitcnt vmcnt(12)" ::: "memory");
        *(float4*)&cstrip[(lane >> 4) * CSTR + (lane & 15) * 4] = c4;
        __builtin_amdgcn_sched_barrier(0);

        // ---- FC from LDS only: acc_j = sum_i c[i] * W[i][j] ----
        const float* cq = &cstrip[q * CSTR];
        float a0 = 0.f, a1 = 0.f;
        #pragma unroll
        for (int t4 = 0; t4 < 16; ++t4) {
            const float4 cv = *(const float4*)&cq[t4 * 4];
            #pragma unroll
            for (int u = 0; u < 4; ++u) {
                const float2 wv = *(const float2*)&Wbase[(t4 * 4 + u) * WSTR];
                a0 = fmaf((&cv.x)[u], wv.x, a0);
                a1 = fmaf((&cv.x)[u], wv.y, a1);
            }
        }

        // reduce across the 4 q-groups, bias + tanh
        a0 += __shfl_xor(a0, 16);  a0 += __shfl_xor(a0, 32);
        a1 += __shfl_xor(a1, 16);  a1 += __shfl_xor(a1, 32);
        a0 = tanhf(a0 + bb.x);     // fc[2*jq]
        a1 = tanhf(a1 + bb.y);     // fc[2*jq+1]

        // ---- fc -> SGPRs ----
        float fc[EMIT_];
        #pragma unroll
        for (int j = 0; j < EMIT_; ++j)
            fc[j] = bcast((j & 1) ? a1 : a0, j >> 1);

        // ---- head parameters (wave-uniform) ----
        float ksq = 0.f;
        #pragma unroll
        for (int m = 0; m < M_; ++m) ksq = fmaf(fc[m], fc[m], ksq);

        const float beta  = log1pf(__expf(fc[20]));          // softplus (|arg|<1)
        const float g     = 1.f / (1.f + __expf(-fc[21]));   // sigmoid
        const float e0 = __expf(fc[22]);
        const float e1 = __expf(fc[23]);
        const float e2 = __expf(fc[24]);
        const float einv = 1.f / (e0 + e1 + e2);
        const float s0 = e0 * einv, s1 = e1 * einv, s2 = e2 * einv;
        const float gamma = 1.f + log1pf(__expf(fc[25]));

        // ---- cosine similarity logits (Mt prefetch landed during FC) ----
        float dot0 = 0.f, msq0 = 0.f, dot1 = 0.f, msq1 = 0.f;
        #pragma unroll
        for (int i = 0; i < 5; ++i) {
            const float4 v = ma[i];
            dot0 = fmaf(fc[4*i+0], v.x, dot0);  msq0 = fmaf(v.x, v.x, msq0);
            dot0 = fmaf(fc[4*i+1], v.y, dot0);  msq0 = fmaf(v.y, v.y, msq0);
            dot0 = fmaf(fc[4*i+2], v.z, dot0);  msq0 = fmaf(v.z, v.z, msq0);
            dot0 = fmaf(fc[4*i+3], v.w, dot0);  msq0 = fmaf(v.w, v.w, msq0);
        }
        #pragma unroll
        for (int i = 0; i < 5; ++i) {
            const float4 v = mb[i];
            dot1 = fmaf(fc[4*i+0], v.x, dot1);  msq1 = fmaf(v.x, v.x, msq1);
            dot1 = fmaf(fc[4*i+1], v.y, dot1);  msq1 = fmaf(v.y, v.y, msq1);
            dot1 = fmaf(fc[4*i+2], v.z, dot1);  msq1 = fmaf(v.z, v.z, msq1);
            dot1 = fmaf(fc[4*i+3], v.w, dot1);  msq1 = fmaf(v.w, v.w, msq1);
        }
        const float l0 = beta * dot0 / sqrtf(ksq * msq0);
        const float l1 = beta * dot1 / sqrtf(ksq * msq1);

        // ---- softmax over 128 logits (2/lane, wave butterfly) ----
        float mx = fmaxf(l0, l1);
        #pragma unroll
        for (int o = 32; o; o >>= 1) mx = fmaxf(mx, __shfl_xor(mx, o));
        const float p0 = __expf(l0 - mx);
        const float p1 = __expf(l1 - mx);
        float sm = p0 + p1;
        #pragma unroll
        for (int o = 32; o; o >>= 1) sm += __shfl_xor(sm, o);
        const float inv_sm = 1.f / sm;

        // ---- interpolate ----
        const float A  = g * (p0 * inv_sm) + (1.f - g) * wp0;   // wg[lane]
        const float Bv = g * (p1 * inv_sm) + (1.f - g) * wp1;   // wg[lane+64]

        // ---- circular shift (S=3) ----
        const float Ap  = __shfl(A,  (lane + 1) & 63);
        const float Bp  = __shfl(Bv, (lane + 1) & 63);
        const float Am  = __shfl(A,  (lane + 63) & 63);
        const float Bm  = __shfl(Bv, (lane + 63) & 63);
        const float A0  = bcast(A, 0);
        const float A63 = bcast(A, 63);
        const float B0  = bcast(Bv, 0);
        const float B63 = bcast(Bv, 63);

        const float np0 = (lane == 63) ? B0  : Ap;   // wg[(lane+1)  % 128]
        const float nm0 = (lane == 0)  ? B63 : Am;   // wg[(lane-1)  % 128]
        const float np1 = (lane == 63) ? A0  : Bp;   // wg[(lane+65) % 128]
        const float nm1 = (lane == 0)  ? A63 : Bm;   // wg[(lane+63) % 128]

        const float wt0 = np0 * s0 + A  * s1 + nm0 * s2;
        const float wt1 = np1 * s0 + Bv * s1 + nm1 * s2;

        // ---- sharpen + normalize ----
        const float wr0 = (wt0 > 0.f) ? __expf(gamma * __logf(wt0)) : 0.f;
        const float wr1 = (wt1 > 0.f) ? __expf(gamma * __logf(wt1)) : 0.f;
        float tot = wr0 + wr1;
        #pragma unroll
        for (int o = 32; o; o >>= 1) tot += __shfl_xor(tot, o);
        const float inv_tot = 1.f / tot;

        float* orow = out + (size_t)b * N_;
        orow[lane]      = wr0 * inv_tot;
        orow[lane + 64] = wr1 * inv_tot;
    }
}

extern "C" void kernel_launch(void* const* d_in, const int* in_sizes, int n_in,
                              void* d_out, int out_size, void* d_ws, size_t ws_size,
                              hipStream_t stream) {
    const float* ctrl   = (const float*)d_in[0];
    const float* w_prev = (const float*)d_in[1];
    const float* Mt     = (const float*)d_in[2];
    const float* W      = (const float*)d_in[3];
    const float* bvec   = (const float*)d_in[4];
    float* out = (float*)d_out;

    ntm_persist_kernel<<<dim3(GRID_), dim3(256), 0, stream>>>(ctrl, w_prev, Mt, W, bvec, out);
}

// Round 12
// 36.018 us; speedup vs baseline: 1.2468x; 1.2468x over previous
//
#include <hip/hip_runtime.h>
#include <math.h>

#define B_    16384
#define C_    256
#define N_    128
#define M_    20
#define S_    3
#define EMIT_ 26
#define WSTR  26          // W row stride in LDS (floats)
#define CSTR  68          // c quarter stride in LDS (floats) -> conflict-free

// Wave-uniform broadcast into an SGPR.
__device__ __forceinline__ float bcast(float v, int l) {
    return __int_as_float(__builtin_amdgcn_readlane(__float_as_int(v), l));
}

// Async global->LDS DMA, 16B/lane (vmcnt-counted, zero VGPR payload).
__device__ __forceinline__ void dma16(const float* g, float* l) {
    __builtin_amdgcn_global_load_lds(
        (const __attribute__((address_space(1))) void*)g,
        (__attribute__((address_space(3))) void*)l, 16, 0, 0);
}

// One WAVE per batch row; 4 rows per 256-thread block; one raw s_barrier.
// vmcnt queue discipline (in-order retirement):
//   [W DMAs (oldest)] [c float4] [bias float2] [10x Mt float4] [2x w_prev]
// The barrier waits vmcnt(12): W/c/bias retired, Mt+wp STAY IN FLIGHT.
// FC then reads ONLY LDS (lgkmcnt) -> never drains the Mt stream.
__global__ __launch_bounds__(256, 5) void ntm_lds_kernel(
    const float* __restrict__ ctrl,    // (B, C)
    const float* __restrict__ w_prev,  // (B, N)
    const float* __restrict__ Mt,      // (B, N, M)
    const float* __restrict__ W,       // (C, EMIT)
    const float* __restrict__ bvec,    // (EMIT)
    float* __restrict__ out)           // (B, N)
{
    const int lane = threadIdx.x & 63;
    const int wid  = threadIdx.x >> 6;
    const int b    = blockIdx.x * 4 + wid;

    __shared__ float W_lds[C_ * WSTR];    // 26624 B, shared by all 4 waves
    __shared__ float c_lds[4][4 * CSTR];  // 4352 B, per-wave strips

    // ---- 1) W -> LDS via DMA, issued FIRST (oldest in vmcnt queue) ----
    // 26 chunks x 1KB; wave `wid` stages chunks wid, wid+4, ...
    for (int k = wid; k < 26; k += 4)
        dma16(W + k * 256 + lane * 4, W_lds + k * 256);
    __builtin_amdgcn_sched_barrier(0);   // nothing hoists above the DMAs

    // ---- 2) c row (1 float4/lane), bias pair, Mt prefetch (regs), w_prev ----
    const int jp = lane & 15;
    const int jq = (jp > 12) ? 12 : jp;   // j-pair 0..12 (lanes 13..15 dup)
    const int q  = lane >> 4;             // C quarter

    const float4 c4 = *(const float4*)(ctrl + (size_t)b * C_ + lane * 4);
    const float2 bb = *(const float2*)(bvec + 2 * jq);

    const float* M0 = Mt + ((size_t)b * N_ + lane) * M_;
    const float* M1 = M0 + (size_t)64 * M_;
    float4 ma[5], mb[5];
    #pragma unroll
    for (int i = 0; i < 5; ++i) ma[i] = *(const float4*)(M0 + 4 * i);
    #pragma unroll
    for (int i = 0; i < 5; ++i) mb[i] = *(const float4*)(M1 + 4 * i);
    const float wp0 = w_prev[(size_t)b * N_ + lane];
    const float wp1 = w_prev[(size_t)b * N_ + lane + 64];
    __builtin_amdgcn_sched_barrier(0);   // pin issue order

    // ---- 3) stage c (same-wave strip), then barrier WITHOUT draining Mt ----
    *(float4*)&c_lds[wid][(lane >> 4) * CSTR + (lane & 15) * 4] = c4;
    __builtin_amdgcn_sched_barrier(0);
    asm volatile("s_waitcnt vmcnt(12) lgkmcnt(0)" ::: "memory"); // W/c/bias done; Mt(10)+wp(2) in flight
    __builtin_amdgcn_s_barrier();
    __builtin_amdgcn_sched_barrier(0);

    // ---- 4) FC from LDS only: acc_j = sum_i c[i] * W[i][j] ----
    const float* cq    = &c_lds[wid][q * CSTR];
    const float* Wbase = &W_lds[(q * 64) * WSTR + 2 * jq];
    float a0 = 0.f, a1 = 0.f;
    #pragma unroll
    for (int t4 = 0; t4 < 16; ++t4) {
        const float4 cv = *(const float4*)&cq[t4 * 4];
        #pragma unroll
        for (int u = 0; u < 4; ++u) {
            const float2 wv = *(const float2*)&Wbase[(t4 * 4 + u) * WSTR];
            a0 = fmaf((&cv.x)[u], wv.x, a0);
            a1 = fmaf((&cv.x)[u], wv.y, a1);
        }
    }

    // reduce across the 4 q-groups, bias + tanh
    a0 += __shfl_xor(a0, 16);  a0 += __shfl_xor(a0, 32);
    a1 += __shfl_xor(a1, 16);  a1 += __shfl_xor(a1, 32);
    a0 = tanhf(a0 + bb.x);     // fc[2*jq]
    a1 = tanhf(a1 + bb.y);     // fc[2*jq+1]

    // ---- 5) fc -> SGPRs ----
    float fc[EMIT_];
    #pragma unroll
    for (int j = 0; j < EMIT_; ++j)
        fc[j] = bcast((j & 1) ? a1 : a0, j >> 1);

    // ---- 6) head parameters (wave-uniform) ----
    float ksq = 0.f;
    #pragma unroll
    for (int m = 0; m < M_; ++m) ksq = fmaf(fc[m], fc[m], ksq);

    const float beta  = log1pf(__expf(fc[20]));          // softplus (|arg|<1)
    const float g     = 1.f / (1.f + __expf(-fc[21]));   // sigmoid
    const float e0 = __expf(fc[22]);
    const float e1 = __expf(fc[23]);
    const float e2 = __expf(fc[24]);
    const float einv = 1.f / (e0 + e1 + e2);
    const float s0 = e0 * einv, s1 = e1 * einv, s2 = e2 * einv;
    const float gamma = 1.f + log1pf(__expf(fc[25]));

    // ---- 7) cosine similarity logits (Mt prefetch landed long ago) ----
    float dot0 = 0.f, msq0 = 0.f, dot1 = 0.f, msq1 = 0.f;
    #pragma unroll
    for (int i = 0; i < 5; ++i) {
        const float4 v = ma[i];
        dot0 = fmaf(fc[4*i+0], v.x, dot0);  msq0 = fmaf(v.x, v.x, msq0);
        dot0 = fmaf(fc[4*i+1], v.y, dot0);  msq0 = fmaf(v.y, v.y, msq0);
        dot0 = fmaf(fc[4*i+2], v.z, dot0);  msq0 = fmaf(v.z, v.z, msq0);
        dot0 = fmaf(fc[4*i+3], v.w, dot0);  msq0 = fmaf(v.w, v.w, msq0);
    }
    #pragma unroll
    for (int i = 0; i < 5; ++i) {
        const float4 v = mb[i];
        dot1 = fmaf(fc[4*i+0], v.x, dot1);  msq1 = fmaf(v.x, v.x, msq1);
        dot1 = fmaf(fc[4*i+1], v.y, dot1);  msq1 = fmaf(v.y, v.y, msq1);
        dot1 = fmaf(fc[4*i+2], v.z, dot1);  msq1 = fmaf(v.z, v.z, msq1);
        dot1 = fmaf(fc[4*i+3], v.w, dot1);  msq1 = fmaf(v.w, v.w, msq1);
    }
    const float l0 = beta * dot0 / sqrtf(ksq * msq0);
    const float l1 = beta * dot1 / sqrtf(ksq * msq1);

    // ---- 8) softmax over 128 logits (2/lane, wave butterfly) ----
    float mx = fmaxf(l0, l1);
    #pragma unroll
    for (int o = 32; o; o >>= 1) mx = fmaxf(mx, __shfl_xor(mx, o));
    const float p0 = __expf(l0 - mx);
    const float p1 = __expf(l1 - mx);
    float sm = p0 + p1;
    #pragma unroll
    for (int o = 32; o; o >>= 1) sm += __shfl_xor(sm, o);
    const float inv_sm = 1.f / sm;

    // ---- 9) interpolate ----
    const float A  = g * (p0 * inv_sm) + (1.f - g) * wp0;   // wg[lane]
    const float Bv = g * (p1 * inv_sm) + (1.f - g) * wp1;   // wg[lane+64]

    // ---- 10) circular shift (S=3) ----
    const float Ap  = __shfl(A,  (lane + 1) & 63);
    const float Bp  = __shfl(Bv, (lane + 1) & 63);
    const float Am  = __shfl(A,  (lane + 63) & 63);
    const float Bm  = __shfl(Bv, (lane + 63) & 63);
    const float A0  = bcast(A, 0);
    const float A63 = bcast(A, 63);
    const float B0  = bcast(Bv, 0);
    const float B63 = bcast(Bv, 63);

    const float np0 = (lane == 63) ? B0  : Ap;   // wg[(lane+1)  % 128]
    const float nm0 = (lane == 0)  ? B63 : Am;   // wg[(lane-1)  % 128]
    const float np1 = (lane == 63) ? A0  : Bp;   // wg[(lane+65) % 128]
    const float nm1 = (lane == 0)  ? A63 : Bm;   // wg[(lane+63) % 128]

    const float wt0 = np0 * s0 + A  * s1 + nm0 * s2;
    const float wt1 = np1 * s0 + Bv * s1 + nm1 * s2;

    // ---- 11) sharpen + normalize ----
    const float wr0 = (wt0 > 0.f) ? __expf(gamma * __logf(wt0)) : 0.f;
    const float wr1 = (wt1 > 0.f) ? __expf(gamma * __logf(wt1)) : 0.f;
    float tot = wr0 + wr1;
    #pragma unroll
    for (int o = 32; o; o >>= 1) tot += __shfl_xor(tot, o);
    const float inv_tot = 1.f / tot;

    float* orow = out + (size_t)b * N_;
    orow[lane]      = wr0 * inv_tot;
    orow[lane + 64] = wr1 * inv_tot;
}

extern "C" void kernel_launch(void* const* d_in, const int* in_sizes, int n_in,
                              void* d_out, int out_size, void* d_ws, size_t ws_size,
                              hipStream_t stream) {
    const float* ctrl   = (const float*)d_in[0];
    const float* w_prev = (const float*)d_in[1];
    const float* Mt     = (const float*)d_in[2];
    const float* W      = (const float*)d_in[3];
    const float* bvec   = (const float*)d_in[4];
    float* out = (float*)d_out;

    ntm_lds_kernel<<<dim3(B_ / 4), dim3(256), 0, stream>>>(ctrl, w_prev, Mt, W, bvec, out);
}